// Round 2
// baseline (4258.942 us; speedup 1.0000x reference)
//
#include <hip/hip_runtime.h>
#include <stdint.h>

// Problem constants
#define Bb   4
#define Tt   32
#define Cc   132
#define Nn   512
#define HID  256
#define KNB  16
#define OUTC 260           // 4 + HID
#define G4   1024          // 4*HID gate rows
#define KP   160           // padded K for P-gemm (132 -> 160, 5 chunks of 32)
#define LDT2 66            // LDS tile row stride (64 + 2 pad)

// Workspace layout (element counts)
#define WP_SZ (1024*KP)          // 163840 f
#define GI_SZ (Bb*Tt*Nn*KNB)     // 1048576 i
#define HT_SZ (Bb*HID*Nn)        // 524288 f
#define CB_SZ (Bb*Nn*HID)        // 524288 f
#define PQ_SZ (Bb*Nn*G4)         // 2097152 f

// Output offsets (floats): layer_output, h_f, c_f, group_ind
#define OFF_HF 17039360
#define OFF_CF 17563648
#define OFF_GI 18087936

// ---------------------------------------------------------------------------
__global__ __launch_bounds__(256) void init_kernel(const float* __restrict__ w,
                                                   float* __restrict__ WP,
                                                   float* __restrict__ hT,
                                                   float* __restrict__ c0) {
  int i = blockIdx.x * 256 + threadIdx.x;
  if (i < WP_SZ) {
    int o = i / KP, c = i % KP;
    float v = 0.f;
    if (c < Cc) {
      v = w[(size_t)o * 392 + c];
      if (c < 4) v -= w[(size_t)o * 392 + 132 + c];
    }
    WP[i] = v;
  } else if (i < WP_SZ + HT_SZ) {
    hT[i - WP_SZ] = 0.f;
  } else if (i < WP_SZ + HT_SZ + CB_SZ) {
    c0[i - WP_SZ - HT_SZ] = 0.f;
  }
}

// ---------------------------------------------------------------------------
// KNN v2: 1024 blocks (B*T*8); block = 64 queries x 4 candidate-subranges of
// 128. Per-thread (f32 d2, idx) insertion chain (strict-less => stable within
// sub). Cross-sub merge via packed u64 (sortable_key<<32 | idx) -> exact
// global (d2, idx) lexicographic order, identical to jax.lax.top_k.
__global__ __launch_bounds__(256) void knn_kernel(const float* __restrict__ x,
                                                  int* __restrict__ gi,
                                                  float* __restrict__ gi_f) {
  int bt = blockIdx.x >> 3;
  int b = bt >> 5, t = bt & 31;
  int q0 = (blockIdx.x & 7) << 6;
  int tr = t > 0 ? t - 1 : 0;
  __shared__ float r0[Nn], r1[Nn], r2[Nn], rr[Nn];
  __shared__ unsigned long long blists[64][4][KNB];  // 32 KB
  const float* xr = x + (size_t)(b * Tt + tr) * Cc * Nn;
  for (int m = threadIdx.x; m < Nn; m += 256) {
    float a0 = xr[m], a1 = xr[Nn + m], a2 = xr[2 * Nn + m];
    r0[m] = a0; r1[m] = a1; r2[m] = a2;
    rr[m] = __fadd_rn(__fadd_rn(__fmul_rn(a0, a0), __fmul_rn(a1, a1)), __fmul_rn(a2, a2));
  }
  __syncthreads();
  int ql = threadIdx.x >> 2;
  int sub = threadIdx.x & 3;
  int n = q0 + ql;
  const float* xq = x + (size_t)(b * Tt + t) * Cc * Nn;
  float q0v = xq[n], q1v = xq[Nn + n], q2v = xq[2 * Nn + n];
  float qq = __fadd_rn(__fadd_rn(__fmul_rn(q0v, q0v), __fmul_rn(q1v, q1v)), __fmul_rn(q2v, q2v));
  float bd[KNB];
  int bi[KNB];
#pragma unroll
  for (int s = 0; s < KNB; ++s) { bd[s] = __int_as_float(0x7F800000); bi[s] = 0; }
  const int m0 = sub << 7;
  for (int mm = 0; mm < 128; ++mm) {
    int m = m0 + mm;
    float in = __fmaf_rn(q2v, r2[m], __fmaf_rn(q1v, r1[m], __fmul_rn(q0v, r0[m])));
    float cd = __fsub_rn(__fadd_rn(qq, rr[m]), __fmul_rn(2.0f, in));
    int ci = m;
#pragma unroll
    for (int s = 0; s < KNB; ++s) {
      bool sw = cd < bd[s];
      float td = sw ? bd[s] : cd;
      int ti = sw ? bi[s] : ci;
      bd[s] = sw ? cd : bd[s];
      bi[s] = sw ? ci : bi[s];
      cd = td; ci = ti;
    }
  }
#pragma unroll
  for (int s = 0; s < KNB; ++s) {
    unsigned int bits = __float_as_uint(bd[s]);
    unsigned int key = (bits & 0x80000000u) ? ~bits : (bits | 0x80000000u);
    blists[ql][sub][s] = ((unsigned long long)key << 32) | (unsigned int)bi[s];
  }
  __syncthreads();
  if (sub == 0) {
    int p0 = 0, p1 = 0, p2 = 0, p3 = 0;
    size_t ob = ((size_t)(b * Tt + t) * Nn + n) * KNB;
#pragma unroll
    for (int s = 0; s < KNB; ++s) {
      unsigned long long h0 = blists[ql][0][p0 & 15];
      unsigned long long h1 = blists[ql][1][p1 & 15];
      unsigned long long h2 = blists[ql][2][p2 & 15];
      unsigned long long h3 = blists[ql][3][p3 & 15];
      unsigned long long mv = h0; int ml = 0;
      if (h1 < mv) { mv = h1; ml = 1; }
      if (h2 < mv) { mv = h2; ml = 2; }
      if (h3 < mv) { mv = h3; ml = 3; }
      p0 += (ml == 0); p1 += (ml == 1); p2 += (ml == 2); p3 += (ml == 3);
      int idx = (int)(mv & 0xFFFFFFFFull);
      gi[ob + s] = idx;
      gi_f[ob + s] = (float)idx;
    }
  }
}

// ---------------------------------------------------------------------------
// 64x64-tile fp32 GEMM body, 256 threads, 4x4 micro. K chunks of 32, LDS
// staged, accumulation order bitwise-identical to the R1 kernel (bias init,
// ascending K, zero padding via FMA with 0 products).
template <bool QM>
__device__ __forceinline__ void gemm_tile(int bid, int tstep,
                                          const float* __restrict__ x,
                                          const float* __restrict__ w,
                                          const float* __restrict__ WP,
                                          const float* __restrict__ hT,
                                          const float* __restrict__ bias,
                                          float* __restrict__ outp,
                                          float* At, float* Bt) {
  const int b = bid >> 7;
  const int to = (bid >> 3) & 15;
  const int tn = bid & 7;
  const int o0 = to << 6, n0 = tn << 6;
  const int tid = threadIdx.x;
  const int tx = tid & 15, ty = tid >> 4;
  float acc[4][4];
#pragma unroll
  for (int i = 0; i < 4; ++i) {
    float bv = QM ? 0.f : bias[o0 + ty * 4 + i];
#pragma unroll
    for (int j = 0; j < 4; ++j) acc[i][j] = bv;
  }
  const int tp = (tstep > 0) ? tstep - 1 : 0;
  const int nch = QM ? 9 : 5;
  const int aor = tid >> 2;        // A: o row 0..63
  const int acb = (tid & 3) << 3;  // A: c base {0,8,16,24}
  const int bcr = tid >> 3;        // B: c row 0..31
  const int bjb = (tid & 7) << 3;  // B: j base {0,8,..,56}
  for (int ch = 0; ch < nch; ++ch) {
    const int kc = ch << 5;
#pragma unroll
    for (int p = 0; p < 2; ++p) {
      int c = acb + (p << 2);
      int gc = kc + c;
      float4 v = make_float4(0.f, 0.f, 0.f, 0.f);
      if (!QM) {
        v = *(const float4*)(WP + (size_t)(o0 + aor) * KP + gc);
      } else {
        if (gc < 260) v = *(const float4*)(w + (size_t)(o0 + aor) * 392 + 132 + gc);
      }
      At[(c + 0) * LDT2 + aor] = v.x;
      At[(c + 1) * LDT2 + aor] = v.y;
      At[(c + 2) * LDT2 + aor] = v.z;
      At[(c + 3) * LDT2 + aor] = v.w;
    }
#pragma unroll
    for (int p = 0; p < 2; ++p) {
      int j = bjb + (p << 2);
      int gc = kc + bcr;
      float4 v = make_float4(0.f, 0.f, 0.f, 0.f);
      if (!QM) {
        if (gc < Cc) v = *(const float4*)(x + ((size_t)(b * Tt + tstep) * Cc + gc) * Nn + n0 + j);
      } else {
        if (gc < 4)        v = *(const float4*)(x + ((size_t)(b * Tt + tp) * Cc + gc) * Nn + n0 + j);
        else if (gc < 260) v = *(const float4*)(hT + ((size_t)b * HID + (gc - 4)) * Nn + n0 + j);
      }
      *(float4*)(Bt + bcr * LDT2 + j) = v;
    }
    __syncthreads();
#pragma unroll
    for (int kk = 0; kk < 32; ++kk) {
      float4 a = *(const float4*)(At + kk * LDT2 + ty * 4);
      float4 bv = *(const float4*)(Bt + kk * LDT2 + tx * 4);
      float av[4] = {a.x, a.y, a.z, a.w};
      float bw[4] = {bv.x, bv.y, bv.z, bv.w};
#pragma unroll
      for (int i = 0; i < 4; ++i)
#pragma unroll
        for (int j = 0; j < 4; ++j)
          acc[i][j] = __fmaf_rn(av[i], bw[j], acc[i][j]);
    }
    __syncthreads();
  }
#pragma unroll
  for (int j = 0; j < 4; ++j) {
    int col = n0 + tx * 4 + j;
    float* row = outp + ((size_t)b * Nn + col) * G4 + o0 + ty * 4;
    *(float4*)row = make_float4(acc[0][j], acc[1][j], acc[2][j], acc[3][j]);
  }
}

__global__ __launch_bounds__(256) void gemm_q_kernel(const float* __restrict__ x,
                                                     const float* __restrict__ w,
                                                     const float* __restrict__ hT,
                                                     float* __restrict__ Qb, int t) {
  __shared__ float At[32 * LDT2], Bt[32 * LDT2];
  gemm_tile<true>(blockIdx.x, t, x, w, nullptr, hT, nullptr, Qb, At, Bt);
}

__global__ __launch_bounds__(256) void gemm_p_kernel(const float* __restrict__ x,
                                                     const float* __restrict__ WP,
                                                     const float* __restrict__ bias,
                                                     float* __restrict__ Pb, int t) {
  __shared__ float At[32 * LDT2], Bt[32 * LDT2];
  gemm_tile<false>(blockIdx.x, t, x, nullptr, WP, nullptr, bias, Pb, At, Bt);
}

// ---------------------------------------------------------------------------
__device__ __forceinline__ float sigm(float v) { return 1.f / (1.f + __expf(-v)); }
__device__ __forceinline__ float tanh_f(float v) { return 1.f - 2.f / (__expf(2.f * v) + 1.f); }

// Fused: blocks [0,512) compute P_{t+1} (64x64 gemm tiles); blocks [512,2560)
// run the pointwise LSTM+maxpool for step t. Disjoint data, different pipes.
__global__ __launch_bounds__(256) void fused_p_lstm(const float* __restrict__ x,
                                                    const float* __restrict__ WP,
                                                    const float* __restrict__ bias,
                                                    float* __restrict__ Pnext,
                                                    const float* __restrict__ Pcur,
                                                    const float* __restrict__ Qb,
                                                    const float* __restrict__ cprev,
                                                    const int* __restrict__ gi,
                                                    float* __restrict__ ccur,
                                                    float* __restrict__ hT,
                                                    float* __restrict__ out, int t) {
  __shared__ float At[32 * LDT2], Bt[32 * LDT2];
  if (blockIdx.x < 512) {
    if (t + 1 < Tt)
      gemm_tile<false>(blockIdx.x, t + 1, x, nullptr, WP, nullptr, bias, Pnext, At, Bt);
    return;
  }
  int bid = blockIdx.x - 512;
  int b = bid >> 9;
  int n = bid & 511;
  int hc = threadIdx.x;
  const float* pr = Pcur + ((size_t)b * Nn + n) * G4;
  float pi = pr[hc], pf = pr[HID + hc], po = pr[2 * HID + hc], pg = pr[3 * HID + hc];
  const int* gr = gi + ((size_t)(b * Tt + t) * Nn + n) * KNB;
  float hmax = -3.4e38f, cmax = -3.4e38f;
#pragma unroll
  for (int k = 0; k < KNB; ++k) {
    int j = gr[k];
    const float* qr = Qb + ((size_t)b * Nn + j) * G4;
    float gi_ = pi + qr[hc];
    float gf_ = pf + qr[HID + hc];
    float go_ = po + qr[2 * HID + hc];
    float gg_ = pg + qr[3 * HID + hc];
    float cg = cprev[((size_t)b * Nn + j) * HID + hc];
    float iv = sigm(gi_), fv = sigm(gf_), ov = sigm(go_);
    float gv = tanh_f(gg_);
    float cn = __fmaf_rn(fv, cg, iv * gv);
    float hn = ov * tanh_f(cn);
    hmax = fmaxf(hmax, hn);
    cmax = fmaxf(cmax, cn);
  }
  ccur[((size_t)b * Nn + n) * HID + hc] = cmax;
  hT[((size_t)b * HID + hc) * Nn + n] = hmax;
  out[((size_t)(b * Tt + t) * OUTC + 4 + hc) * Nn + n] = hmax;
}

// ---------------------------------------------------------------------------
__global__ __launch_bounds__(256) void pos_copy(const float* __restrict__ x,
                                                float* __restrict__ out) {
  int i = blockIdx.x * 256 + threadIdx.x;  // B*T*4*N = 262144
  int n = i & 511;
  int c = (i >> 9) & 3;
  int bt = i >> 11;
  out[((size_t)bt * OUTC + c) * Nn + n] = x[((size_t)bt * Cc + c) * Nn + n];
}

__global__ __launch_bounds__(256) void finalize(const float* __restrict__ hT,
                                                const float* __restrict__ cfin,
                                                float* __restrict__ out) {
  int i = blockIdx.x * 256 + threadIdx.x;  // < 524288
  out[OFF_HF + i] = hT[i];
  int n = i & 511;
  int rest = i >> 9;
  int hc = rest & 255;
  int b = rest >> 8;
  out[OFF_CF + i] = cfin[((size_t)b * Nn + n) * HID + hc];
}

// ---------------------------------------------------------------------------
extern "C" void kernel_launch(void* const* d_in, const int* in_sizes, int n_in,
                              void* d_out, int out_size, void* d_ws, size_t ws_size,
                              hipStream_t stream) {
  const float* x    = (const float*)d_in[0];
  const float* w    = (const float*)d_in[1];
  const float* bias = (const float*)d_in[2];
  float* out = (float*)d_out;

  float* WP  = (float*)d_ws;
  int*   gi  = (int*)(WP + WP_SZ);
  float* hT  = (float*)(gi + GI_SZ);
  float* c0  = hT + HT_SZ;
  float* c1  = c0 + CB_SZ;
  float* Pb0 = c1 + CB_SZ;
  float* Pb1 = Pb0 + PQ_SZ;
  float* Qb  = Pb1 + PQ_SZ;

  init_kernel<<<4736, 256, 0, stream>>>(w, WP, hT, c0);
  knn_kernel<<<1024, 256, 0, stream>>>(x, gi, out + OFF_GI);
  pos_copy<<<1024, 256, 0, stream>>>(x, out);
  gemm_p_kernel<<<512, 256, 0, stream>>>(x, WP, bias, Pb0, 0);

  float* cp = c0;
  float* cn = c1;
  for (int t = 0; t < Tt; ++t) {
    float* Pcur  = (t & 1) ? Pb1 : Pb0;
    float* Pnext = (t & 1) ? Pb0 : Pb1;
    gemm_q_kernel<<<512, 256, 0, stream>>>(x, w, hT, Qb, t);
    fused_p_lstm<<<2560, 256, 0, stream>>>(x, WP, bias, Pnext, Pcur, Qb, cp, gi, cn, hT, out, t);
    float* tmp = cp; cp = cn; cn = tmp;
  }
  finalize<<<2048, 256, 0, stream>>>(hT, cp, out);
}